// Round 12
// baseline (945.729 us; speedup 1.0000x reference)
//
#include <hip/hip_runtime.h>
#include <hip/hip_bf16.h>
#include <stdint.h>

typedef __bf16 bf16x8 __attribute__((ext_vector_type(8)));
typedef float  f32x4  __attribute__((ext_vector_type(4)));
typedef unsigned short u16;

__device__ __forceinline__ u16 f2bf(float f) {
    return __builtin_bit_cast(u16, __float2bfloat16(f));
}

__device__ __forceinline__ void gload16(const void* g, void* l) {
    __builtin_amdgcn_global_load_lds(
        (const __attribute__((address_space(1))) void*)g,
        (__attribute__((address_space(3))) void*)l,
        16, 0, 0);
}

// ---------------- quantization pipeline ----------------

__global__ void zero3_k(unsigned int* p) {
    if (threadIdx.x < 3) p[threadIdx.x] = 0u;
}

__global__ void maxabs_k(const float* __restrict__ w, int n, unsigned int* __restrict__ out) {
    const int tid = threadIdx.x;
    float m = 0.f;
    for (int i = blockIdx.x * blockDim.x + tid; i < n; i += gridDim.x * blockDim.x)
        m = fmaxf(m, fabsf(w[i]));
    #pragma unroll
    for (int off = 32; off > 0; off >>= 1)
        m = fmaxf(m, __shfl_down(m, off));
    __shared__ float red[4];
    if ((tid & 63) == 0) red[tid >> 6] = m;
    __syncthreads();
    if (tid == 0) {
        m = fmaxf(fmaxf(red[0], red[1]), fmaxf(red[2], red[3]));
        atomicMax(out, __float_as_uint(m));  // all values >=0: uint order == float order
    }
}

// w_q = clip(rint(w/scale), -n, n)*scale (fp32, matches jnp), emitted in
// MFMA-frag-PACKED layout: chunk[(k/32)*(rows/16) + r/16][lane][8] where
// lane = (r&15) + ((k>>3)&3)*16, elem = k&7. A wave's B-frag load is then
// 64 lanes x consecutive 16B = one coalesced 1KB block. (R6-verified.)
__global__ void quant_pack_k(const float* __restrict__ w, int rows, int K, int l2k8,
                             const unsigned int* __restrict__ maxbits, float qn,
                             u16* __restrict__ out) {
    const float scale = __uint_as_float(*maxbits) / qn;
    const int nchunk = rows * (K >> 3);
    const int NB16 = rows >> 4;
    for (int i = blockIdx.x * blockDim.x + threadIdx.x; i < nchunk;
         i += gridDim.x * blockDim.x) {
        const int r  = i >> l2k8;
        const int k8 = i & ((1 << l2k8) - 1);
        const float* src = w + (size_t)r * K + (k8 << 3);
        u16 tmp[8];
        #pragma unroll
        for (int j = 0; j < 8; ++j) {
            float q = rintf(src[j] / scale);     // RNE == jnp.round
            q = fminf(qn, fmaxf(-qn, q));
            tmp[j] = f2bf(q * scale);
        }
        const size_t chunk = ((size_t)(k8 >> 2) * NB16 + (r >> 4)) * 64
                             + (r & 15) + ((k8 & 3) << 4);
        *(uint4*)(out + chunk * 8) = *(const uint4*)tmp;
    }
}

__global__ void cvt_k(const float* __restrict__ x, u16* __restrict__ o, long n) {
    const long stride = (long)gridDim.x * blockDim.x * 4;
    for (long i = ((long)blockIdx.x * blockDim.x + threadIdx.x) * 4; i < n; i += stride) {
        float4 v = *(const float4*)(x + i);
        unsigned int lo = (unsigned int)f2bf(v.x) | ((unsigned int)f2bf(v.y) << 16);
        unsigned int hi = (unsigned int)f2bf(v.z) | ((unsigned int)f2bf(v.w) << 16);
        *(uint2*)(o + i) = make_uint2(lo, hi);
    }
}

// ---------------- GEMM: C = A(MxK) * B(NxK)^T + bias, LeakyReLU ----------------
// 256x256 tile, BK=64, 8 waves (2M x 4N), 16x16x32 MFMA (R8 frag maps).
// B NEVER touches LDS: packed-frag B loads go global->reg (8 coalesced 16B/lane
// loads per wave per tile, L2/L3-served), prefetched one tile ahead into named
// reg sets (rule 20). LDS holds only A (2 x 32KB dbuf): traffic/tile = 128KB
// read + 32KB write (~1800cy) < MFMA (~2480cy) -> MFMA-bound reachable (R8-R11
// were DS-bound at 256KB/tile). Sync ledger per tile (simulated, closes):
//   head BARR (WAR: A slot (kt+1)&1 reads done during tile kt-1)
//   STG A(kt+1) [4 loads] ; LOAD_B(kt+1) [8 reg loads]
//   vmcnt(12) == certify A(kt)+B(kt) (exactly the 12 newest remain)
//   BARR (A(kt) visible) ; then 2 phases {8 ds_read_b128; LGKM0; 16 MFMA}.
// Prologue: STG A(0)+LOAD_B(0); vmcnt(8) certifies A(0). Last tile vmcnt(0).
// Swizzle (verified 0-conflict): granule g ^= (row>>1)&7, source pre-swizzled
// (rule 21). Grid: R8's XCD-bijective swizzle (A-panel L2 reuse — the fix for
// R6's 3x FETCH explosion).

#define BARR  __builtin_amdgcn_s_barrier()
#define LGKM0 do { asm volatile("s_waitcnt lgkmcnt(0)" ::: "memory");          \
                   __builtin_amdgcn_sched_barrier(0); } while (0)
#define FENCE asm volatile("" ::: "memory")

// stage A half-tile h of tile kt (dest linear, src col pre-swizzled)
#define STG(kt, h)                                                             \
  do {                                                                         \
    u16* _d = smem + (((kt) & 1) << 14) + ((h) << 13) + wave * 512;            \
    const size_t _go = (size_t)((h) * 128) * K + (size_t)(kt) * 64;            \
    gload16(gA + _go,                  _d);                                    \
    gload16(gA + _go + (size_t)64 * K, _d + 4096);                             \
  } while (0)

// load tile kt's 8 B-frags into D0 (nh=0), D1 (nh=1); frag idx n2*2+ks
#define LOAD_B(kt, D0, D1)                                                     \
  do {                                                                         \
    const u16* _p = pBb + (size_t)(2 * (kt)) * kStrideB;                       \
    _Pragma("unroll") for (int ks = 0; ks < 2; ++ks)                           \
      _Pragma("unroll") for (int n2 = 0; n2 < 2; ++n2) {                       \
        D0[n2 * 2 + ks] = *(const bf16x8*)(_p + ks * kStrideB + n2 * 2048);    \
        D1[n2 * 2 + ks] = *(const bf16x8*)(_p + ks * kStrideB + 4096 + n2 * 2048);\
      }                                                                        \
  } while (0)

#define RD_A(kt, mh)                                                           \
  do {                                                                         \
    const u16* _p = smem + (((kt) & 1) << 14) + ((mh) << 13) + rowA;           \
    _Pragma("unroll") for (int m2 = 0; m2 < 4; ++m2) {                         \
        afr[m2 * 2]     = *(const bf16x8*)(_p + m2 * 2048 + g0);               \
        afr[m2 * 2 + 1] = *(const bf16x8*)(_p + m2 * 2048 + g1);               \
    }                                                                          \
  } while (0)

#define MM(mh, nh, BS)                                                         \
  do {                                                                         \
    __builtin_amdgcn_s_setprio(1);                                             \
    _Pragma("unroll") for (int m2 = 0; m2 < 4; ++m2)                           \
      _Pragma("unroll") for (int n2 = 0; n2 < 2; ++n2) {                       \
        acc[(mh)*4+m2][(nh)*2+n2] = __builtin_amdgcn_mfma_f32_16x16x32_bf16(   \
            afr[m2*2],     BS[n2*2],   acc[(mh)*4+m2][(nh)*2+n2], 0, 0, 0);    \
        acc[(mh)*4+m2][(nh)*2+n2] = __builtin_amdgcn_mfma_f32_16x16x32_bf16(   \
            afr[m2*2+1],   BS[n2*2+1], acc[(mh)*4+m2][(nh)*2+n2], 0, 0, 0);    \
      }                                                                        \
    __builtin_amdgcn_s_setprio(0);                                             \
  } while (0)

#define KTILE(kt, VMSTR, DO_STAGE, CUR0, CUR1, NXT0, NXT1)                     \
  do {                                                                         \
    FENCE; BARR; FENCE;        /* WAR: A slot (kt+1)&1 reads finished */       \
    if (DO_STAGE) { STG((kt)+1, 0); STG((kt)+1, 1);                            \
                    LOAD_B((kt)+1, NXT0, NXT1); }                              \
    asm volatile("s_waitcnt vmcnt(" VMSTR ")" ::: "memory");                   \
    FENCE; BARR; FENCE;        /* A(kt) visible to all waves */                \
    RD_A(kt, 0);                                                               \
    LGKM0;                                                                     \
    MM(0, 0, CUR0);                                                            \
    MM(0, 1, CUR1);                                                            \
    RD_A(kt, 1);                                                               \
    LGKM0;                                                                     \
    MM(1, 0, CUR0);                                                            \
    __builtin_amdgcn_sched_barrier(0);                                         \
    MM(1, 1, CUR1);                                                            \
  } while (0)

template<int BF16OUT>
__global__ __launch_bounds__(512, 2)
void gemmbr(const u16* __restrict__ A, const u16* __restrict__ pB,
            const float* __restrict__ bias, void* __restrict__ Cv,
            int M, int Nn, int K)
{
    __shared__ __align__(128) u16 smem[32768];  // A only: 2 dbuf x 256 x 64

    const int tid  = threadIdx.x;
    const int lane = tid & 63;
    const int wave = tid >> 6;
    const int wm = wave >> 2;   // 0..1
    const int wn = wave & 3;    // 0..3

    // XCD-aware bijective swizzle (gridDim.x % 8 == 0)
    const int nbx = Nn >> 8;
    const int cpx = gridDim.x >> 3;
    const int swz = (blockIdx.x & 7) * cpx + (blockIdx.x >> 3);
    const int bn = (swz % nbx) << 8;
    const int bm = (swz / nbx) << 8;

    // A staging source: thread t -> row t>>3 of a 64-row chunk, granule t&7;
    // source granule pre-swizzled: (t&7) ^ ((r>>1)&7) == (t&7) ^ ((t>>4)&7)
    const int scol = (((tid & 7) ^ ((tid >> 4) & 7)) << 3);
    const u16* gA = A + (size_t)(bm + (tid >> 3)) * K + scol;

    // packed-B: chunk idx = k32*NB16 + (Nrow/16); wave's frag (nh,n2,ks) at
    // chunk [ (2kt+ks)*NB16 + bnC + nh*8 + n2*4 + wn ], lane offset lane*8.
    const int NB16 = Nn >> 4;
    const size_t kStrideB = (size_t)NB16 * 512;
    const u16* pBb = pB + ((size_t)((bn >> 4) + wn)) * 512 + (lane << 3);

    // A frag ds_read constants (u16 elems)
    const int fr = lane & 15;
    const int g0 = (((lane >> 4)    ) ^ (fr >> 1)) << 3;   // ks=0 granule
    const int g1 = (((lane >> 4) + 4) ^ (fr >> 1)) << 3;   // ks=1 granule
    const int rowA = (wm * 16 + fr) << 6;                  // + m2*2048 per m-frag

    f32x4 acc[8][4] = {};
    bf16x8 afr[8], cB0[4], cB1[4], nB0[4], nB1[4];

    const int NT = K >> 6;   // 16 or 32 (even)

    // prologue: A(0) staged + B(0) in regs; vmcnt(8) certifies A(0) (8 B newer)
    STG(0, 0); STG(0, 1);
    LOAD_B(0, cB0, cB1);
    asm volatile("s_waitcnt vmcnt(8)" ::: "memory");
    BARR;

    for (int kt = 0; kt < NT - 2; kt += 2) {
        KTILE(kt,     "12", true, cB0, cB1, nB0, nB1);
        KTILE(kt + 1, "12", true, nB0, nB1, cB0, cB1);
    }
    KTILE(NT - 2, "12", true, cB0, cB1, nB0, nB1);   // stages A/B(NT-1)
    KTILE(NT - 1, "0",  false, nB0, nB1, cB0, cB1);  // drain

    // ---- epilogue: scalar stores (R8-proven) ----
    // C/D frag layout (m89): col = lane&15, row = (lane>>4)*4 + j
    // frag map: row = (m>>2)*128 + (m&3)*32 + wm*16; col = n*64 + wn*16
    const int crow = (lane >> 4) << 2;
    const int ccol = lane & 15;
    #pragma unroll
    for (int n = 0; n < 4; ++n) {
        const int col = bn + n * 64 + wn * 16 + ccol;
        const float bv = bias[col];
        #pragma unroll
        for (int m = 0; m < 8; ++m) {
            const int row0 = bm + (m >> 2) * 128 + (m & 3) * 32 + wm * 16 + crow;
            #pragma unroll
            for (int j = 0; j < 4; ++j) {
                float v = acc[m][n][j] + bv;
                v = (v >= 0.f) ? v : 0.01f * v;
                if (BF16OUT) {
                    ((u16*)Cv)[(size_t)(row0 + j) * Nn + col] = f2bf(v);
                } else {
                    ((float*)Cv)[(size_t)(row0 + j) * Nn + col] = v;
                }
            }
        }
    }
}

// ---------------- launch ----------------

extern "C" void kernel_launch(void* const* d_in, const int* in_sizes, int n_in,
                              void* d_out, int out_size, void* d_ws, size_t ws_size,
                              hipStream_t stream) {
    const float* x  = (const float*)d_in[0];
    const float* W0 = (const float*)d_in[1];
    const float* b0 = (const float*)d_in[2];
    const float* W1 = (const float*)d_in[3];
    const float* b1 = (const float*)d_in[4];
    const float* W2 = (const float*)d_in[5];
    const float* b2 = (const float*)d_in[6];

    const int N = 32768, D0 = 1024, D1 = 2048;

    char* ws = (char*)d_ws;
    u16* xbf = (u16*)ws;  ws += (size_t)N * D0 * 2;
    u16* h0  = (u16*)ws;  ws += (size_t)N * D1 * 2;
    u16* h1  = (u16*)ws;  ws += (size_t)N * D1 * 2;
    u16* w0q = (u16*)ws;  ws += (size_t)D1 * D0 * 2;
    u16* w1q = (u16*)ws;  ws += (size_t)D1 * D1 * 2;
    u16* w2q = (u16*)ws;  ws += (size_t)D1 * D1 * 2;
    unsigned int* scales = (unsigned int*)ws;

    zero3_k<<<1, 64, 0, stream>>>(scales);
    maxabs_k<<<256, 256, 0, stream>>>(W0, D1 * D0, scales + 0);
    maxabs_k<<<256, 256, 0, stream>>>(W1, D1 * D1, scales + 1);
    maxabs_k<<<256, 256, 0, stream>>>(W2, D1 * D1, scales + 2);
    // packed-frag quantized weights (l2k8 = log2(K/8))
    quant_pack_k<<<2048, 256, 0, stream>>>(W0, D1, D0, 7, scales + 0, 127.f, w0q);
    quant_pack_k<<<2048, 256, 0, stream>>>(W1, D1, D1, 8, scales + 1, 7.f, w1q);
    quant_pack_k<<<2048, 256, 0, stream>>>(W2, D1, D1, 8, scales + 2, 7.f, w2q);
    cvt_k<<<4096, 256, 0, stream>>>(x, xbf, (long)N * D0);

    const int blocks = (D1 / 256) * (N / 256);   // 8 * 128 = 1024, %8 == 0
    gemmbr<1><<<blocks, 512, 0, stream>>>(xbf, w0q, b0, h0, N, D1, D0);
    gemmbr<1><<<blocks, 512, 0, stream>>>(h0, w1q, b1, h1, N, D1, D1);
    gemmbr<0><<<blocks, 512, 0, stream>>>(h1, w2q, b2, d_out, N, D1, D1);
}

// Round 13
// 723.036 us; speedup vs baseline: 1.3080x; 1.3080x over previous
//
#include <hip/hip_runtime.h>
#include <hip/hip_bf16.h>
#include <stdint.h>

typedef __bf16 bf16x8 __attribute__((ext_vector_type(8)));
typedef float  f32x4  __attribute__((ext_vector_type(4)));
typedef unsigned short u16;

__device__ __forceinline__ u16 f2bf(float f) {
    return __builtin_bit_cast(u16, __float2bfloat16(f));
}

__device__ __forceinline__ void gload16(const void* g, void* l) {
    __builtin_amdgcn_global_load_lds(
        (const __attribute__((address_space(1))) void*)g,
        (__attribute__((address_space(3))) void*)l,
        16, 0, 0);
}

// ---------------- quantization pipeline ----------------

__global__ void zero3_k(unsigned int* p) {
    if (threadIdx.x < 3) p[threadIdx.x] = 0u;
}

__global__ void maxabs_k(const float* __restrict__ w, int n, unsigned int* __restrict__ out) {
    const int tid = threadIdx.x;
    float m = 0.f;
    for (int i = blockIdx.x * blockDim.x + tid; i < n; i += gridDim.x * blockDim.x)
        m = fmaxf(m, fabsf(w[i]));
    #pragma unroll
    for (int off = 32; off > 0; off >>= 1)
        m = fmaxf(m, __shfl_down(m, off));
    __shared__ float red[4];
    if ((tid & 63) == 0) red[tid >> 6] = m;
    __syncthreads();
    if (tid == 0) {
        m = fmaxf(fmaxf(red[0], red[1]), fmaxf(red[2], red[3]));
        atomicMax(out, __float_as_uint(m));  // all values >=0: uint order == float order
    }
}

// w_q = clip(rint(w/scale), -n, n) * scale, scale = max|w|/n  (all fp32, matches jnp)
__global__ void quant_k(const float* __restrict__ w, int n,
                        const unsigned int* __restrict__ maxbits, float qn,
                        u16* __restrict__ out) {
    const float scale = __uint_as_float(*maxbits) / qn;
    for (int i = blockIdx.x * blockDim.x + threadIdx.x; i < n; i += gridDim.x * blockDim.x) {
        float q = rintf(w[i] / scale);          // RNE == jnp.round
        q = fminf(qn, fmaxf(-qn, q));
        out[i] = f2bf(q * scale);
    }
}

__global__ void cvt_k(const float* __restrict__ x, u16* __restrict__ o, long n) {
    const long stride = (long)gridDim.x * blockDim.x * 4;
    for (long i = ((long)blockIdx.x * blockDim.x + threadIdx.x) * 4; i < n; i += stride) {
        float4 v = *(const float4*)(x + i);
        unsigned int lo = (unsigned int)f2bf(v.x) | ((unsigned int)f2bf(v.y) << 16);
        unsigned int hi = (unsigned int)f2bf(v.z) | ((unsigned int)f2bf(v.w) << 16);
        *(uint2*)(o + i) = make_uint2(lo, hi);
    }
}

// ---------------- GEMM: C = A(MxK) * B(NxK)^T + bias, LeakyReLU ----------------
// R8 skeleton (271us / 1014 TF proven) minus the 4 TAIL barriers: 4 barriers
// per K-64 tile (mid-phase only, each right after its VM4). Safety (drift <=1
// phase): arrival at phase-p's barrier requires passing phase-(p-1)'s LGKM0,
// so every wave's reads of the slot being overwritten completed before any
// wave's STG to it; staged-data visibility = same VM4->BARR chain as R8
// (prologue VM4 certifies A0,B0(0); P0-VM4 -> B1(kt); P1-VM4 -> A1(kt);
// P3-VM4 -> A0,B0(kt+1)). Tail-barrier removal lets SIMD-partner waves drift
// one phase apart so one wave's MFMA covers the other's ds_reads (m114).
// 256x256 tile, BK=64, 8 waves (2M x 4N), 16x16x32 MFMA, interleaved frags;
// swizzle granule g ^= (row>>1)&7 src-pre-swizzled (0-conflict, R8-verified);
// XCD-bijective block swizzle; scalar epilogue.

#define BARR  __builtin_amdgcn_s_barrier()
#define VM4   asm volatile("s_waitcnt vmcnt(4)" ::: "memory")
#define LGKM0 do { asm volatile("s_waitcnt lgkmcnt(0)" ::: "memory");          \
                   __builtin_amdgcn_sched_barrier(0); } while (0)
#define FENCE asm volatile("" ::: "memory")

// stage half-tile: ISA=1 -> A, h = row-half; dest linear, src col pre-swizzled
#define STG(kt, ISA, h)                                                        \
  do {                                                                         \
    const u16* _s = (ISA) ? gA : gB;                                           \
    u16* _d = smem + ((ISA) ? 0 : 32768) + (((kt) & 1) << 14) + ((h) << 13)    \
              + wave * 512;                                                    \
    const size_t _go = (size_t)((h) * 128) * K + (size_t)(kt) * 64;            \
    gload16(_s + _go,                 _d);                                     \
    gload16(_s + _go + (size_t)64 * K, _d + 4096);                             \
  } while (0)

#define RD_A(kt, mh)                                                           \
  do {                                                                         \
    const u16* _p = smem + (((kt) & 1) << 14) + ((mh) << 13) + rowA;           \
    _Pragma("unroll") for (int m2 = 0; m2 < 4; ++m2) {                         \
        afr[m2 * 2]     = *(const bf16x8*)(_p + m2 * 2048 + g0);               \
        afr[m2 * 2 + 1] = *(const bf16x8*)(_p + m2 * 2048 + g1);               \
    }                                                                          \
  } while (0)

#define RD_B(kt, nh, DST)                                                      \
  do {                                                                         \
    const u16* _p = smem + 32768 + (((kt) & 1) << 14) + ((nh) << 13) + rowB;   \
    _Pragma("unroll") for (int n2 = 0; n2 < 2; ++n2) {                         \
        DST[n2 * 2]     = *(const bf16x8*)(_p + n2 * 4096 + g0);               \
        DST[n2 * 2 + 1] = *(const bf16x8*)(_p + n2 * 4096 + g1);               \
    }                                                                          \
  } while (0)

#define MM(mh, nh, BS)                                                         \
  do {                                                                         \
    __builtin_amdgcn_s_setprio(1);                                             \
    _Pragma("unroll") for (int m2 = 0; m2 < 4; ++m2)                           \
      _Pragma("unroll") for (int n2 = 0; n2 < 2; ++n2) {                       \
        acc[(mh)*4+m2][(nh)*2+n2] = __builtin_amdgcn_mfma_f32_16x16x32_bf16(   \
            afr[m2*2],     BS[n2*2],   acc[(mh)*4+m2][(nh)*2+n2], 0, 0, 0);    \
        acc[(mh)*4+m2][(nh)*2+n2] = __builtin_amdgcn_mfma_f32_16x16x32_bf16(   \
            afr[m2*2+1],   BS[n2*2+1], acc[(mh)*4+m2][(nh)*2+n2], 0, 0, 0);    \
      }                                                                        \
    __builtin_amdgcn_s_setprio(0);                                             \
  } while (0)

template<int BF16OUT>
__global__ __launch_bounds__(512, 2)
void gemm8x(const u16* __restrict__ A, const u16* __restrict__ B,
            const float* __restrict__ bias, void* __restrict__ Cv,
            int M, int Nn, int K)
{
    __shared__ __align__(128) u16 smem[65536];  // A: [0,32768) B: [32768,65536)

    const int tid  = threadIdx.x;
    const int lane = tid & 63;
    const int wave = tid >> 6;
    const int wm = wave >> 2;   // 0..1
    const int wn = wave & 3;    // 0..3

    // XCD-aware bijective swizzle (gridDim.x % 8 == 0)
    const int nbx = Nn >> 8;
    const int cpx = gridDim.x >> 3;
    const int swz = (blockIdx.x & 7) * cpx + (blockIdx.x >> 3);
    const int bn = (swz % nbx) << 8;
    const int bm = (swz / nbx) << 8;

    // staging source: thread t covers row (t>>3) of a 64-row chunk, granule t&7;
    // source granule pre-swizzled: (t&7) ^ ((r>>1)&7) == (t&7) ^ ((t>>4)&7)
    const int scol = (((tid & 7) ^ ((tid >> 4) & 7)) << 3);
    const u16* gA = A + (size_t)(bm + (tid >> 3)) * K + scol;
    const u16* gB = B + (size_t)(bn + (tid >> 3)) * K + scol;

    // frag ds_read constants (u16 elems)
    const int fr = lane & 15;
    const int g0 = (((lane >> 4)    ) ^ (fr >> 1)) << 3;   // ks=0 granule
    const int g1 = (((lane >> 4) + 4) ^ (fr >> 1)) << 3;   // ks=1 granule
    const int rowA = (wm * 16 + fr) << 6;                  // + m2*2048 per m-frag
    const int rowB = (wn * 16 + fr) << 6;                  // + n2*4096 per n-frag

    f32x4 acc[8][4] = {};
    bf16x8 afr[8], b0f[4], b1f[4];

    const int NT = K >> 6;   // 16 or 32

    // prologue: tile 0's half-tiles in ledger order A0,B0,B1,A1;
    // VM4 certifies A0(0),B0(0) before P0's reads (R10 lesson).
    STG(0, 1, 0); STG(0, 0, 0); STG(0, 0, 1); STG(0, 1, 1);
    VM4;
    BARR;

    for (int kt = 0; kt < NT - 1; ++kt) {
        // P0: quadrant (0,0)
        RD_A(kt, 0); RD_B(kt, 0, b0f);
        STG(kt + 1, 1, 0);
        VM4; BARR; LGKM0;           // VM4 certifies B1(kt)
        MM(0, 0, b0f);
        FENCE;
        // P1: quadrant (0,1)
        RD_B(kt, 1, b1f);
        STG(kt + 1, 0, 0);
        VM4; BARR; LGKM0;           // VM4 certifies A1(kt)
        MM(0, 1, b1f);
        FENCE;
        // P2: quadrant (1,0)
        RD_A(kt, 1);
        STG(kt + 1, 0, 1);
        BARR; LGKM0;
        MM(1, 0, b0f);
        FENCE;
        // P3: quadrant (1,1)
        STG(kt + 1, 1, 1);
        VM4; BARR;                  // VM4 certifies A0(kt+1),B0(kt+1)
        __builtin_amdgcn_sched_barrier(0);
        MM(1, 1, b1f);
        FENCE;
    }
    {   // last tile: no staging; drain ledger 4 -> 2 -> 0
        const int kt = NT - 1;
        RD_A(kt, 0); RD_B(kt, 0, b0f);
        asm volatile("s_waitcnt vmcnt(2)" ::: "memory");   // certifies B1
        BARR; LGKM0;
        MM(0, 0, b0f);
        FENCE;
        RD_B(kt, 1, b1f);
        asm volatile("s_waitcnt vmcnt(0)" ::: "memory");   // certifies A1
        BARR; LGKM0;
        MM(0, 1, b1f);
        FENCE;
        RD_A(kt, 1);
        BARR; LGKM0;
        MM(1, 0, b0f);
        FENCE;
        __builtin_amdgcn_sched_barrier(0);
        MM(1, 1, b1f);
    }

    // ---- epilogue: scalar stores (R2/R8-proven) ----
    // C/D frag layout (m89): col = lane&15, row = (lane>>4)*4 + j
    // interleaved frag map: row = (m>>2)*128 + (m&3)*32 + wm*16; col = n*64 + wn*16
    const int crow = (lane >> 4) << 2;
    const int ccol = lane & 15;
    #pragma unroll
    for (int n = 0; n < 4; ++n) {
        const int col = bn + n * 64 + wn * 16 + ccol;
        const float bv = bias[col];
        #pragma unroll
        for (int m = 0; m < 8; ++m) {
            const int row0 = bm + (m >> 2) * 128 + (m & 3) * 32 + wm * 16 + crow;
            #pragma unroll
            for (int j = 0; j < 4; ++j) {
                float v = acc[m][n][j] + bv;
                v = (v >= 0.f) ? v : 0.01f * v;
                if (BF16OUT) {
                    ((u16*)Cv)[(size_t)(row0 + j) * Nn + col] = f2bf(v);
                } else {
                    ((float*)Cv)[(size_t)(row0 + j) * Nn + col] = v;
                }
            }
        }
    }
}

// ---------------- launch ----------------

extern "C" void kernel_launch(void* const* d_in, const int* in_sizes, int n_in,
                              void* d_out, int out_size, void* d_ws, size_t ws_size,
                              hipStream_t stream) {
    const float* x  = (const float*)d_in[0];
    const float* W0 = (const float*)d_in[1];
    const float* b0 = (const float*)d_in[2];
    const float* W1 = (const float*)d_in[3];
    const float* b1 = (const float*)d_in[4];
    const float* W2 = (const float*)d_in[5];
    const float* b2 = (const float*)d_in[6];

    const int N = 32768, D0 = 1024, D1 = 2048;

    char* ws = (char*)d_ws;
    u16* xbf = (u16*)ws;  ws += (size_t)N * D0 * 2;
    u16* h0  = (u16*)ws;  ws += (size_t)N * D1 * 2;
    u16* h1  = (u16*)ws;  ws += (size_t)N * D1 * 2;
    u16* w0q = (u16*)ws;  ws += (size_t)D1 * D0 * 2;
    u16* w1q = (u16*)ws;  ws += (size_t)D1 * D1 * 2;
    u16* w2q = (u16*)ws;  ws += (size_t)D1 * D1 * 2;
    unsigned int* scales = (unsigned int*)ws;

    zero3_k<<<1, 64, 0, stream>>>(scales);
    maxabs_k<<<256, 256, 0, stream>>>(W0, D1 * D0, scales + 0);
    maxabs_k<<<256, 256, 0, stream>>>(W1, D1 * D1, scales + 1);
    maxabs_k<<<256, 256, 0, stream>>>(W2, D1 * D1, scales + 2);
    quant_k<<<2048, 256, 0, stream>>>(W0, D1 * D0, scales + 0, 127.f, w0q);
    quant_k<<<2048, 256, 0, stream>>>(W1, D1 * D1, scales + 1, 7.f, w1q);
    quant_k<<<2048, 256, 0, stream>>>(W2, D1 * D1, scales + 2, 7.f, w2q);
    cvt_k<<<4096, 256, 0, stream>>>(x, xbf, (long)N * D0);

    const int blocks = (D1 / 256) * (N / 256);   // 8 * 128 = 1024, %8 == 0
    gemm8x<1><<<blocks, 512, 0, stream>>>(xbf, w0q, b0, h0, N, D1, D0);
    gemm8x<1><<<blocks, 512, 0, stream>>>(h0, w1q, b1, h1, N, D1, D1);
    gemm8x<0><<<blocks, 512, 0, stream>>>(h1, w2q, b2, d_out, N, D1, D1);
}